// Round 1
// baseline (613.898 us; speedup 1.0000x reference)
//
#include <hip/hip_runtime.h>
#include <hip/hip_bf16.h>

#define NB 8
#define NC 256
#define NH 128
#define NW 128
#define NR 512
#define NGROUPS 16
#define HP 130
#define NPIX (NH*NW)

// workspace offsets (in floats)
#define OFF_KERN  0            // NB*NC*9 = 18432
#define OFF_GAMMA 18432        // 2048
#define OFF_BETA  20480        // 2048
#define OFF_ATT   22528        // 2048
#define OFF_A     24576        // 2048
#define OFF_B2    26624        // 2048
#define OFF_WT    28672        // 65536
#define OFF_GP    94208        // NB*16*130*130 = 2163200

__device__ __forceinline__ float leakyf(float v) { return v > 0.f ? v : 0.1f * v; }

__device__ __forceinline__ unsigned short f2bf(float f) {
    unsigned u = __float_as_uint(f);
    unsigned r = (u + 0x7FFFu + ((u >> 16) & 1u)) >> 16;
    return (unsigned short)r;
}
__device__ __forceinline__ float bf2f(unsigned short s) {
    return __uint_as_float(((unsigned)s) << 16);
}

// ---------------- K1: per-sample parameter vectors ----------------
__global__ __launch_bounds__(256) void k_params(
    const float* __restrict__ rep, const float* __restrict__ w_key,
    const float* __restrict__ w_gamma, const float* __restrict__ w_beta,
    const float* __restrict__ w_ca1, const float* __restrict__ prelu_a,
    const float* __restrict__ w_ca2, float* __restrict__ ws)
{
    __shared__ float rep_s[NR];
    __shared__ float hmid_s[128];
    const int b = blockIdx.x, t = threadIdx.x;
    rep_s[t]       = rep[b*NR + t];
    rep_s[t + 256] = rep[b*NR + t + 256];
    __syncthreads();
    const float4* rep4 = (const float4*)rep_s;

    // kern: 2304 rows
    for (int idx = t; idx < NC*9; idx += 256) {
        const float4* w4 = (const float4*)(w_key + idx*NR);
        float acc = 0.f;
        #pragma unroll 8
        for (int i = 0; i < NR/4; i++) {
            float4 a = rep4[i], w = w4[i];
            acc += a.x*w.x + a.y*w.y + a.z*w.z + a.w*w.w;
        }
        ws[OFF_KERN + b*NC*9 + idx] = leakyf(acc);
    }
    // gamma
    {
        const float4* w4 = (const float4*)(w_gamma + t*NR);
        float acc = 0.f;
        #pragma unroll 8
        for (int i = 0; i < NR/4; i++) {
            float4 a = rep4[i], w = w4[i];
            acc += a.x*w.x + a.y*w.y + a.z*w.z + a.w*w.w;
        }
        ws[OFF_GAMMA + b*NC + t] = leakyf(acc);
    }
    // beta
    {
        const float4* w4 = (const float4*)(w_beta + t*NR);
        float acc = 0.f;
        #pragma unroll 8
        for (int i = 0; i < NR/4; i++) {
            float4 a = rep4[i], w = w4[i];
            acc += a.x*w.x + a.y*w.y + a.z*w.z + a.w*w.w;
        }
        ws[OFF_BETA + b*NC + t] = leakyf(acc);
    }
    // hmid (128) with PReLU
    if (t < 128) {
        const float4* w4 = (const float4*)(w_ca1 + t*NR);
        float acc = 0.f;
        #pragma unroll 8
        for (int i = 0; i < NR/4; i++) {
            float4 a = rep4[i], w = w4[i];
            acc += a.x*w.x + a.y*w.y + a.z*w.z + a.w*w.w;
        }
        float pa = prelu_a[0];
        hmid_s[t] = acc > 0.f ? acc : pa * acc;
    }
    __syncthreads();
    // att = sigmoid(hmid @ w_ca2^T)
    {
        const float* w = w_ca2 + t*128;
        float acc = 0.f;
        #pragma unroll 8
        for (int i = 0; i < 128; i++) acc += hmid_s[i] * w[i];
        ws[OFF_ATT + b*NC + t] = 1.f / (1.f + expf(-acc));
    }
}

// ---------------- K2: transpose w_conv2 -> Wt[c][o] ----------------
__global__ __launch_bounds__(256) void k_transpose(
    const float* __restrict__ W, float* __restrict__ ws)
{
    const int o = blockIdx.x, c = threadIdx.x;
    ws[OFF_WT + c*NC + o] = W[o*NC + c];
}

// ---------------- K3: padded group sums (reflect) ----------------
__global__ __launch_bounds__(128) void k_gsum(
    const float* __restrict__ x, float* __restrict__ ws)
{
    const int bid = blockIdx.x;            // bg*130 + yy
    const int yy = bid % HP;
    const int bg = bid / HP;               // b*16 + g
    int sy = yy - 1; if (sy < 0) sy = -sy; if (sy > NH-1) sy = 2*(NH-1) - sy;
    const float* xbase = x + (size_t)bg * 16 * NPIX + (size_t)sy * NW;
    float* gp = ws + OFF_GP + (size_t)bid * HP;
    for (int xx = threadIdx.x; xx < HP; xx += 128) {
        int sx = xx - 1; if (sx < 0) sx = -sx; if (sx > NW-1) sx = 2*(NW-1) - sx;
        float s = 0.f;
        #pragma unroll
        for (int k = 0; k < 16; k++) s += xbase[(size_t)k * NPIX + sx];
        gp[xx] = s;
    }
}

// ---------------- K4: instance-norm stats from Gp, fold affine ----------------
__global__ __launch_bounds__(256) void k_stats(float* __restrict__ ws)
{
    const int g = blockIdx.x, b = blockIdx.y, t = threadIdx.x;
    __shared__ float kern_s[16*9];
    __shared__ float red[256*32];
    if (t < 144) kern_s[t] = ws[OFF_KERN + (b*NC + g*16)*9 + t];
    __syncthreads();

    float s[16], q[16];
    #pragma unroll
    for (int i = 0; i < 16; i++) { s[i] = 0.f; q[i] = 0.f; }

    const float* gp = ws + OFF_GP + (size_t)(b*16 + g) * HP * HP;
    for (int p = t; p < NPIX; p += 256) {
        const int y = p >> 7, xc = p & 127;
        const float* pa = gp + y*HP + xc;
        const float p0 = pa[0],    p1 = pa[1],      p2 = pa[2];
        const float p3 = pa[HP],   p4 = pa[HP+1],   p5 = pa[HP+2];
        const float p6 = pa[2*HP], p7 = pa[2*HP+1], p8 = pa[2*HP+2];
        #pragma unroll
        for (int ch = 0; ch < 16; ch++) {
            const float* k9 = kern_s + ch*9;
            float v = k9[0]*p0 + k9[1]*p1 + k9[2]*p2
                    + k9[3]*p3 + k9[4]*p4 + k9[5]*p5
                    + k9[6]*p6 + k9[7]*p7 + k9[8]*p8;
            s[ch] += v; q[ch] += v*v;
        }
    }
    #pragma unroll
    for (int ch = 0; ch < 16; ch++) { red[t*32 + ch] = s[ch]; red[t*32 + 16 + ch] = q[ch]; }
    for (int st = 128; st >= 1; st >>= 1) {
        __syncthreads();
        if (t < st) {
            #pragma unroll
            for (int v = 0; v < 32; v++) red[t*32 + v] += red[(t+st)*32 + v];
        }
    }
    __syncthreads();
    if (t < 16) {
        const float S = red[t], Q = red[16 + t];
        const float mean = S * (1.f/16384.f);
        const float var  = Q * (1.f/16384.f) - mean*mean;
        const float inv  = rsqrtf(var + 1e-5f);
        const int c = g*16 + t;
        const float ga = ws[OFF_GAMMA + b*NC + c];
        const float be = ws[OFF_BETA  + b*NC + c];
        const float a  = ga * inv;
        ws[OFF_A  + b*NC + c] = a;
        ws[OFF_B2 + b*NC + c] = be - mean * a;
    }
}

// ---------------- K5: main fused kernel ----------------
// block: 256 threads, handles (b, y, 64-pixel half-row)
__global__ __launch_bounds__(256, 2) void k_main(
    const float* __restrict__ x, const float* __restrict__ ws,
    const float* __restrict__ bias, float* __restrict__ out)
{
    __shared__ float gp_t[16][3][66];          // 12672 B
    __shared__ float kern_s[NC*9];             // 9216 B
    __shared__ float a_s[NC], b2_s[NC], att_s[NC]; // 3072 B
    __shared__ unsigned short z_s[NC][64];     // 32768 B
    __shared__ float wstage[16][256];          // 16384 B

    const int t = threadIdx.x;
    const int x0 = blockIdx.x * 64, y = blockIdx.y, b = blockIdx.z;

    // stage Gp tile (16 groups x 3 rows x 66 cols)
    const float* gp = ws + OFF_GP + (size_t)b * 16 * HP * HP;
    for (int i = t; i < 16*3*66; i += 256) {
        const int g = i / 198, rem = i - g*198;
        const int r = rem / 66, xl = rem - r*66;
        gp_t[g][r][xl] = gp[(size_t)(g*HP + y + r)*HP + x0 + xl];
    }
    for (int i = t; i < NC*9; i += 256) kern_s[i] = ws[OFF_KERN + b*NC*9 + i];
    a_s[t]   = ws[OFF_A   + b*NC + t];
    b2_s[t]  = ws[OFF_B2  + b*NC + t];
    att_s[t] = ws[OFF_ATT + b*NC + t];
    __syncthreads();

    // phase B: z = relu(a*conv + b2) + x*att   (wave w handles channels w*64..w*64+63)
    const int wave = t >> 6, lane = t & 63;
    for (int i = 0; i < 64; i++) {
        const int c = wave*64 + i;
        const int g = c >> 4;
        const float xv = x[(size_t)((b*NC + c)*NH + y)*NW + x0 + lane];
        const float* k9 = kern_s + c*9;
        const float* g0 = gp_t[g][0];
        const float* g1 = gp_t[g][1];
        const float* g2 = gp_t[g][2];
        float conv = k9[0]*g0[lane] + k9[1]*g0[lane+1] + k9[2]*g0[lane+2]
                   + k9[3]*g1[lane] + k9[4]*g1[lane+1] + k9[5]*g1[lane+2]
                   + k9[6]*g2[lane] + k9[7]*g2[lane+1] + k9[8]*g2[lane+2];
        float z = fmaxf(fmaf(a_s[c], conv, b2_s[c]), 0.f) + xv * att_s[c];
        z_s[c][lane] = f2bf(z);
    }

    // phase C: out[o][p] = sum_c Wt[c][o] * z[c][p]
    float acc[64];
    #pragma unroll
    for (int i = 0; i < 64; i++) acc[i] = 0.f;
    const int p4 = (t & 15) * 4;
    const int ob = (t >> 4) * 16;

    for (int c0 = 0; c0 < NC; c0 += 16) {
        __syncthreads();
        for (int i = t; i < 16*256; i += 256) {
            const int cc = i >> 8, col = i & 255;
            wstage[cc][col] = ws[OFF_WT + (c0 + cc)*NC + col];
        }
        __syncthreads();
        #pragma unroll
        for (int cc = 0; cc < 16; cc++) {
            const ushort4 zu = *reinterpret_cast<const ushort4*>(&z_s[c0 + cc][p4]);
            const float zf0 = bf2f(zu.x), zf1 = bf2f(zu.y), zf2 = bf2f(zu.z), zf3 = bf2f(zu.w);
            const float4 wA = *reinterpret_cast<const float4*>(&wstage[cc][ob]);
            const float4 wB = *reinterpret_cast<const float4*>(&wstage[cc][ob + 4]);
            const float4 wC = *reinterpret_cast<const float4*>(&wstage[cc][ob + 8]);
            const float4 wD = *reinterpret_cast<const float4*>(&wstage[cc][ob + 12]);
            const float wv[16] = {wA.x,wA.y,wA.z,wA.w, wB.x,wB.y,wB.z,wB.w,
                                  wC.x,wC.y,wC.z,wC.w, wD.x,wD.y,wD.z,wD.w};
            #pragma unroll
            for (int o = 0; o < 16; o++) {
                acc[o*4+0] = fmaf(wv[o], zf0, acc[o*4+0]);
                acc[o*4+1] = fmaf(wv[o], zf1, acc[o*4+1]);
                acc[o*4+2] = fmaf(wv[o], zf2, acc[o*4+2]);
                acc[o*4+3] = fmaf(wv[o], zf3, acc[o*4+3]);
            }
        }
    }

    // write
    #pragma unroll
    for (int o = 0; o < 16; o++) {
        const int oc = ob + o;
        const float bo = bias[oc];
        float4 v = make_float4(acc[o*4+0] + bo, acc[o*4+1] + bo,
                               acc[o*4+2] + bo, acc[o*4+3] + bo);
        *reinterpret_cast<float4*>(&out[(size_t)((b*NC + oc)*NH + y)*NW + x0 + p4]) = v;
    }
}

extern "C" void kernel_launch(void* const* d_in, const int* in_sizes, int n_in,
                              void* d_out, int out_size, void* d_ws, size_t ws_size,
                              hipStream_t stream) {
    const float* x       = (const float*)d_in[0];
    const float* rep     = (const float*)d_in[1];
    const float* w_key   = (const float*)d_in[2];
    const float* w_gamma = (const float*)d_in[3];
    const float* w_beta  = (const float*)d_in[4];
    const float* w_ca1   = (const float*)d_in[5];
    const float* prelu_a = (const float*)d_in[6];
    const float* w_ca2   = (const float*)d_in[7];
    const float* w_conv2 = (const float*)d_in[8];
    const float* b_conv2 = (const float*)d_in[9];
    float* out = (float*)d_out;
    float* ws  = (float*)d_ws;

    k_params<<<NB, 256, 0, stream>>>(rep, w_key, w_gamma, w_beta, w_ca1, prelu_a, w_ca2, ws);
    k_transpose<<<NC, 256, 0, stream>>>(w_conv2, ws);
    k_gsum<<<NB*NGROUPS*HP, 128, 0, stream>>>(x, ws);
    k_stats<<<dim3(NGROUPS, NB), 256, 0, stream>>>(ws);
    k_main<<<dim3(2, NH, NB), 256, 0, stream>>>(x, ws, b_conv2, out);
}

// Round 2
// 307.571 us; speedup vs baseline: 1.9960x; 1.9960x over previous
//
#include <hip/hip_runtime.h>
#include <hip/hip_bf16.h>

#define NB 8
#define NC 256
#define NH 128
#define NW 128
#define NR 512
#define NGROUPS 16
#define HP 130
#define NPIX (NH*NW)

// workspace offsets (in floats)
#define OFF_KERN  0            // NB*NC*9 = 18432
#define OFF_GAMMA 18432        // 2048
#define OFF_BETA  20480        // 2048
#define OFF_ATT   22528        // 2048
#define OFF_A     24576        // 2048
#define OFF_B2    26624        // 2048
#define OFF_GP    94208        // NB*16*130*130 = 2163200
#define OFF_APACK 2257408      // 2*8*16*64*8 bf16 = 131072 ushort = 65536 floats
#define OFF_PART  2322944      // 8*16*4*32 = 16384 floats

typedef __attribute__((ext_vector_type(8))) short bf16x8;
typedef __attribute__((ext_vector_type(4))) float f32x4;

__device__ __forceinline__ float leakyf(float v) { return v > 0.f ? v : 0.1f * v; }

__device__ __forceinline__ unsigned short f2bf(float f) {
    unsigned u = __float_as_uint(f);
    unsigned r = (u + 0x7FFFu + ((u >> 16) & 1u)) >> 16;
    return (unsigned short)r;
}
__device__ __forceinline__ float bf2f(unsigned short s) {
    return __uint_as_float(((unsigned)s) << 16);
}

// ---------------- K1: per-sample parameter vectors ----------------
__global__ __launch_bounds__(256) void k_params(
    const float* __restrict__ rep, const float* __restrict__ w_key,
    const float* __restrict__ w_gamma, const float* __restrict__ w_beta,
    const float* __restrict__ w_ca1, const float* __restrict__ prelu_a,
    const float* __restrict__ w_ca2, float* __restrict__ ws)
{
    __shared__ float rep_s[NR];
    __shared__ float hmid_s[128];
    const int b = blockIdx.x, t = threadIdx.x;
    rep_s[t]       = rep[b*NR + t];
    rep_s[t + 256] = rep[b*NR + t + 256];
    __syncthreads();
    const float4* rep4 = (const float4*)rep_s;

    for (int idx = t; idx < NC*9; idx += 256) {
        const float4* w4 = (const float4*)(w_key + idx*NR);
        float acc = 0.f;
        #pragma unroll 8
        for (int i = 0; i < NR/4; i++) {
            float4 a = rep4[i], w = w4[i];
            acc += a.x*w.x + a.y*w.y + a.z*w.z + a.w*w.w;
        }
        ws[OFF_KERN + b*NC*9 + idx] = leakyf(acc);
    }
    {
        const float4* w4 = (const float4*)(w_gamma + t*NR);
        float acc = 0.f;
        #pragma unroll 8
        for (int i = 0; i < NR/4; i++) {
            float4 a = rep4[i], w = w4[i];
            acc += a.x*w.x + a.y*w.y + a.z*w.z + a.w*w.w;
        }
        ws[OFF_GAMMA + b*NC + t] = leakyf(acc);
    }
    {
        const float4* w4 = (const float4*)(w_beta + t*NR);
        float acc = 0.f;
        #pragma unroll 8
        for (int i = 0; i < NR/4; i++) {
            float4 a = rep4[i], w = w4[i];
            acc += a.x*w.x + a.y*w.y + a.z*w.z + a.w*w.w;
        }
        ws[OFF_BETA + b*NC + t] = leakyf(acc);
    }
    if (t < 128) {
        const float4* w4 = (const float4*)(w_ca1 + t*NR);
        float acc = 0.f;
        #pragma unroll 8
        for (int i = 0; i < NR/4; i++) {
            float4 a = rep4[i], w = w4[i];
            acc += a.x*w.x + a.y*w.y + a.z*w.z + a.w*w.w;
        }
        float pa = prelu_a[0];
        hmid_s[t] = acc > 0.f ? acc : pa * acc;
    }
    __syncthreads();
    {
        const float* w = w_ca2 + t*128;
        float acc = 0.f;
        #pragma unroll 8
        for (int i = 0; i < 128; i++) acc += hmid_s[i] * w[i];
        ws[OFF_ATT + b*NC + t] = 1.f / (1.f + expf(-acc));
    }
}

// ---------------- K2: pack w_conv2 into MFMA A-fragment order (hi/lo bf16) ----------------
// Apack layout (ushort): idx = (((ks*16 + mt)*2 + hl)*64 + lane)*8 + j
// element = W[mt*16 + (lane&15)][ks*32 + (lane>>4)*8 + j]
__global__ __launch_bounds__(256) void k_pack(
    const float* __restrict__ W, float* __restrict__ ws)
{
    const int idx = blockIdx.x * 256 + threadIdx.x;   // 0..65535
    const int j    = idx & 7;
    const int lane = (idx >> 3) & 63;
    const int mt   = (idx >> 9) & 15;
    const int ks   = idx >> 13;
    const int m = mt*16 + (lane & 15);
    const int k = ks*32 + (lane >> 4)*8 + j;
    const float w = W[m*NC + k];
    const unsigned short hi = f2bf(w);
    const float rem = w - bf2f(hi);
    const unsigned short lo = f2bf(rem);
    unsigned short* ap = (unsigned short*)(ws + OFF_APACK);
    const int base = (((ks*16 + mt)*2)*64 + lane)*8 + j;
    ap[base]       = hi;
    ap[base + 512] = lo;
}

// ---------------- K3: padded group sums (reflect) ----------------
__global__ __launch_bounds__(256) void k_gsum(
    const float* __restrict__ x, float* __restrict__ ws)
{
    const int bid = blockIdx.x;            // bg*65 + pair
    const int pair = bid % 65;
    const int bg = bid / 65;               // b*16 + g
    const int t = threadIdx.x;
    const int half = t >> 7, tt = t & 127;
    const int yy = pair*2 + half;          // 0..129
    int sy = yy - 1; if (sy < 0) sy = -sy; if (sy > NH-1) sy = 2*(NH-1) - sy;
    const float* xbase = x + (size_t)bg * 16 * NPIX + (size_t)sy * NW;
    float* gp = ws + OFF_GP + ((size_t)bg * HP + yy) * HP;
    for (int xx = tt; xx < HP; xx += 128) {
        int sx = xx - 1; if (sx < 0) sx = -sx; if (sx > NW-1) sx = 2*(NW-1) - sx;
        float s = 0.f;
        #pragma unroll
        for (int k = 0; k < 16; k++) s += xbase[(size_t)k * NPIX + sx];
        gp[xx] = s;
    }
}

// ---------------- K4: instance-norm partial stats from Gp ----------------
__global__ __launch_bounds__(256) void k_stats(float* __restrict__ ws)
{
    const int g = blockIdx.x, b = blockIdx.y, chunk = blockIdx.z, t = threadIdx.x;
    __shared__ float kern_s[16*9];
    __shared__ float red[256*32];
    if (t < 144) kern_s[t] = ws[OFF_KERN + (b*NC + g*16)*9 + t];
    __syncthreads();

    float s[16], q[16];
    #pragma unroll
    for (int i = 0; i < 16; i++) { s[i] = 0.f; q[i] = 0.f; }

    const float* gp = ws + OFF_GP + (size_t)(b*16 + g) * HP * HP;
    const int p0b = chunk * 4096;
    for (int pi = 0; pi < 16; pi++) {
        const int p = p0b + pi*256 + t;
        const int y = p >> 7, xc = p & 127;
        const float* pa = gp + y*HP + xc;
        const float p0 = pa[0],    p1 = pa[1],      p2 = pa[2];
        const float p3 = pa[HP],   p4 = pa[HP+1],   p5 = pa[HP+2];
        const float p6 = pa[2*HP], p7 = pa[2*HP+1], p8 = pa[2*HP+2];
        #pragma unroll
        for (int ch = 0; ch < 16; ch++) {
            const float* k9 = kern_s + ch*9;
            float v = k9[0]*p0 + k9[1]*p1 + k9[2]*p2
                    + k9[3]*p3 + k9[4]*p4 + k9[5]*p5
                    + k9[6]*p6 + k9[7]*p7 + k9[8]*p8;
            s[ch] += v; q[ch] += v*v;
        }
    }
    #pragma unroll
    for (int ch = 0; ch < 16; ch++) { red[t*32 + ch] = s[ch]; red[t*32 + 16 + ch] = q[ch]; }
    for (int st = 128; st >= 1; st >>= 1) {
        __syncthreads();
        if (t < st) {
            #pragma unroll
            for (int v = 0; v < 32; v++) red[t*32 + v] += red[(t+st)*32 + v];
        }
    }
    __syncthreads();
    if (t < 32) {
        ws[OFF_PART + (size_t)((b*16 + g)*4 + chunk)*32 + t] = red[t];
    }
}

// ---------------- K5: finalize stats -> a, b2 ----------------
__global__ __launch_bounds__(256) void k_fin(float* __restrict__ ws)
{
    const int b = blockIdx.x, c = threadIdx.x;
    const int g = c >> 4, ch = c & 15;
    const float* part = ws + OFF_PART + (size_t)(b*16 + g)*4*32;
    float S = 0.f, Q = 0.f;
    #pragma unroll
    for (int k = 0; k < 4; k++) { S += part[k*32 + ch]; Q += part[k*32 + 16 + ch]; }
    const float mean = S * (1.f/16384.f);
    const float var  = Q * (1.f/16384.f) - mean*mean;
    const float inv  = rsqrtf(var + 1e-5f);
    const float ga = ws[OFF_GAMMA + b*NC + c];
    const float be = ws[OFF_BETA  + b*NC + c];
    const float a  = ga * inv;
    ws[OFF_A  + b*NC + c] = a;
    ws[OFF_B2 + b*NC + c] = be - mean * a;
}

// ---------------- K6: main fused kernel (phase B VALU + phase C MFMA) ----------------
// block: 256 threads = 4 waves; tile = (b, y, 64 px) x 256 out-channels
__global__ __launch_bounds__(256) void k_main(
    const float* __restrict__ x, const float* __restrict__ ws,
    const float* __restrict__ bias, float* __restrict__ out)
{
    // z_t: 64 px rows x 256 ch bf16, XOR-swizzled: byte = px*512 + (ch*2 ^ ((px&7)<<4))
    __shared__ unsigned short z_t[64*256];     // 32768 B
    __shared__ float bias_s[NC];               // 1024 B

    const int t = threadIdx.x;
    const int wave = t >> 6, lane = t & 63;
    const int x0 = blockIdx.x * 64, y = blockIdx.y, b = blockIdx.z;

    bias_s[t] = bias[t];

    char* zb = (char*)z_t;

    // ---- phase B: z = relu(a*conv + b2) + x*att, wave handles channels wave*64..+63 ----
    const float* kernG = ws + OFF_KERN + b*NC*9;
    const float* aG    = ws + OFF_A   + b*NC;
    const float* b2G   = ws + OFF_B2  + b*NC;
    const float* attG  = ws + OFF_ATT + b*NC;
    const float* gpB   = ws + OFF_GP + (size_t)b * 16 * HP * HP;
    const float* xB    = x + (size_t)b * NC * NPIX + (size_t)y * NW + x0 + lane;

    #pragma unroll
    for (int gi = 0; gi < 4; gi++) {
        const int g = wave*4 + gi;
        const float* gpr = gpB + ((size_t)g * HP + y) * HP + x0 + lane;
        const float p0 = gpr[0],    p1 = gpr[1],      p2 = gpr[2];
        const float p3 = gpr[HP],   p4 = gpr[HP+1],   p5 = gpr[HP+2];
        const float p6 = gpr[2*HP], p7 = gpr[2*HP+1], p8 = gpr[2*HP+2];
        #pragma unroll
        for (int ci = 0; ci < 16; ci++) {
            const int c = g*16 + ci;
            const float* k9 = kernG + c*9;   // wave-uniform -> s_load
            float conv = k9[0]*p0 + k9[1]*p1 + k9[2]*p2
                       + k9[3]*p3 + k9[4]*p4 + k9[5]*p5
                       + k9[6]*p6 + k9[7]*p7 + k9[8]*p8;
            const float xv = xB[(size_t)c * NPIX];
            float z = fmaxf(fmaf(aG[c], conv, b2G[c]), 0.f) + xv * attG[c];
            const int byte = lane*512 + ((c*2) ^ ((lane & 7) << 4));
            *(unsigned short*)(zb + byte) = f2bf(z);
        }
    }
    __syncthreads();

    // ---- phase C: out[o][px] = sum_c W[o][c] * z[c][px] via MFMA ----
    const unsigned short* ap = (const unsigned short*)(ws + OFF_APACK);
    f32x4 acc[4][4];
    #pragma unroll
    for (int mi = 0; mi < 4; mi++)
        #pragma unroll
        for (int ni = 0; ni < 4; ni++)
            acc[mi][ni] = (f32x4){0.f, 0.f, 0.f, 0.f};

    for (int ks = 0; ks < 8; ks++) {
        bf16x8 bfr[4];
        #pragma unroll
        for (int ni = 0; ni < 4; ni++) {
            const int px = ni*16 + (lane & 15);
            const int byte = px*512 + ((ks*64 + (lane >> 4)*16) ^ ((px & 7) << 4));
            bfr[ni] = *(const bf16x8*)(zb + byte);
        }
        #pragma unroll
        for (int mi = 0; mi < 4; mi++) {
            const int mt = wave*4 + mi;
            const bf16x8 ahi = *(const bf16x8*)(ap + ((size_t)((ks*16 + mt)*2    )*64 + lane)*8);
            const bf16x8 alo = *(const bf16x8*)(ap + ((size_t)((ks*16 + mt)*2 + 1)*64 + lane)*8);
            #pragma unroll
            for (int ni = 0; ni < 4; ni++) {
                acc[mi][ni] = __builtin_amdgcn_mfma_f32_16x16x32_bf16(ahi, bfr[ni], acc[mi][ni], 0, 0, 0);
                acc[mi][ni] = __builtin_amdgcn_mfma_f32_16x16x32_bf16(alo, bfr[ni], acc[mi][ni], 0, 0, 0);
            }
        }
    }

    // ---- epilogue: C layout col=lane&15 (px), row=(lane>>4)*4+reg (out) ----
    #pragma unroll
    for (int mi = 0; mi < 4; mi++) {
        const int o_base = wave*64 + mi*16 + (lane >> 4)*4;
        #pragma unroll
        for (int ni = 0; ni < 4; ni++) {
            const int px = x0 + ni*16 + (lane & 15);
            #pragma unroll
            for (int r = 0; r < 4; r++) {
                const int o = o_base + r;
                out[((size_t)(b*NC + o) * NH + y) * NW + px] = acc[mi][ni][r] + bias_s[o];
            }
        }
    }
}

extern "C" void kernel_launch(void* const* d_in, const int* in_sizes, int n_in,
                              void* d_out, int out_size, void* d_ws, size_t ws_size,
                              hipStream_t stream) {
    const float* x       = (const float*)d_in[0];
    const float* rep     = (const float*)d_in[1];
    const float* w_key   = (const float*)d_in[2];
    const float* w_gamma = (const float*)d_in[3];
    const float* w_beta  = (const float*)d_in[4];
    const float* w_ca1   = (const float*)d_in[5];
    const float* prelu_a = (const float*)d_in[6];
    const float* w_ca2   = (const float*)d_in[7];
    const float* w_conv2 = (const float*)d_in[8];
    const float* b_conv2 = (const float*)d_in[9];
    float* out = (float*)d_out;
    float* ws  = (float*)d_ws;

    k_params<<<NB, 256, 0, stream>>>(rep, w_key, w_gamma, w_beta, w_ca1, prelu_a, w_ca2, ws);
    k_pack<<<256, 256, 0, stream>>>(w_conv2, ws);
    k_gsum<<<NB*NGROUPS*65, 256, 0, stream>>>(x, ws);
    k_stats<<<dim3(NGROUPS, NB, 4), 256, 0, stream>>>(ws);
    k_fin<<<NB, 256, 0, stream>>>(ws);
    k_main<<<dim3(2, NH, NB), 256, 0, stream>>>(x, ws, b_conv2, out);
}

// Round 3
// 151.342 us; speedup vs baseline: 4.0564x; 2.0323x over previous
//
#include <hip/hip_runtime.h>
#include <hip/hip_bf16.h>

#define NB 8
#define NC 256
#define NH 128
#define NW 128
#define NR 512
#define NGROUPS 16
#define HP 130
#define NPIX (NH*NW)

// workspace offsets (in floats)
#define OFF_KERN  0            // NB*NC*9 = 18432
#define OFF_GAMMA 18432        // 2048
#define OFF_BETA  20480        // 2048
#define OFF_ATT   22528        // 2048
#define OFF_A     24576        // 2048
#define OFF_B2    26624        // 2048
#define OFF_HMID  28672        // NB*128 = 1024 (reusing old WT region)
#define OFF_GP    94208        // NB*16*130*130 = 2163200
#define OFF_APACK 2257408      // 2*8*16*64*8 bf16 = 131072 ushort = 65536 floats
#define OFF_PART  2322944      // 8*16*4*32 = 16384 floats

typedef __attribute__((ext_vector_type(8))) short bf16x8;
typedef __attribute__((ext_vector_type(4))) float f32x4;

__device__ __forceinline__ float leakyf(float v) { return v > 0.f ? v : 0.1f * v; }

__device__ __forceinline__ unsigned short f2bf(float f) {
    unsigned u = __float_as_uint(f);
    unsigned r = (u + 0x7FFFu + ((u >> 16) & 1u)) >> 16;
    return (unsigned short)r;
}
__device__ __forceinline__ float bf2f(unsigned short s) {
    return __uint_as_float(((unsigned)s) << 16);
}

// ---------------- K1: all per-sample GEMV rows, row-parallel ----------------
// rows 0..2303 kern (leaky), 2304..2559 gamma (leaky), 2560..2815 beta (leaky),
// 2816..2943 hmid (PReLU). 4 threads per row, 128 elems each, shfl reduce.
__global__ __launch_bounds__(256) void k_params(
    const float* __restrict__ rep, const float* __restrict__ w_key,
    const float* __restrict__ w_gamma, const float* __restrict__ w_beta,
    const float* __restrict__ w_ca1, const float* __restrict__ prelu_a,
    float* __restrict__ ws)
{
    __shared__ float rep_s[NR];
    const int b = blockIdx.y, t = threadIdx.x;
    rep_s[t]       = rep[b*NR + t];
    rep_s[t + 256] = rep[b*NR + t + 256];
    __syncthreads();

    const int r = blockIdx.x * 64 + (t >> 2);   // 0..2943
    const int part = t & 3;
    const float* wrow;
    if (r < 2304)      wrow = w_key   + (size_t)r * NR;
    else if (r < 2560) wrow = w_gamma + (size_t)(r - 2304) * NR;
    else if (r < 2816) wrow = w_beta  + (size_t)(r - 2560) * NR;
    else               wrow = w_ca1   + (size_t)(r - 2816) * NR;

    const float4* w4 = (const float4*)wrow + part*32;
    const float4* r4 = (const float4*)rep_s + part*32;
    float acc = 0.f;
    #pragma unroll
    for (int i = 0; i < 32; i++) {
        float4 a = r4[i], w = w4[i];
        acc += a.x*w.x + a.y*w.y + a.z*w.z + a.w*w.w;
    }
    acc += __shfl_xor(acc, 1, 64);
    acc += __shfl_xor(acc, 2, 64);

    if (part == 0) {
        if (r < 2816) {
            const float v = leakyf(acc);
            if (r < 2304)      ws[OFF_KERN  + b*NC*9 + r]        = v;
            else if (r < 2560) ws[OFF_GAMMA + b*NC + r - 2304]   = v;
            else               ws[OFF_BETA  + b*NC + r - 2560]   = v;
        } else {
            const float pa = prelu_a[0];
            ws[OFF_HMID + b*128 + r - 2816] = acc > 0.f ? acc : pa * acc;
        }
    }
}

// ---------------- K2: pack w_conv2 into MFMA A-fragment order (hi/lo bf16) ----------------
// Apack layout (ushort): idx = (((ks*16 + mt)*2 + hl)*64 + lane)*8 + j
// element = W[mt*16 + (lane&15)][ks*32 + (lane>>4)*8 + j]
__global__ __launch_bounds__(256) void k_pack(
    const float* __restrict__ W, float* __restrict__ ws)
{
    const int idx = blockIdx.x * 256 + threadIdx.x;   // 0..65535
    const int j    = idx & 7;
    const int lane = (idx >> 3) & 63;
    const int mt   = (idx >> 9) & 15;
    const int ks   = idx >> 13;
    const int m = mt*16 + (lane & 15);
    const int k = ks*32 + (lane >> 4)*8 + j;
    const float w = W[m*NC + k];
    const unsigned short hi = f2bf(w);
    const float rem = w - bf2f(hi);
    const unsigned short lo = f2bf(rem);
    unsigned short* ap = (unsigned short*)(ws + OFF_APACK);
    const int base = (((ks*16 + mt)*2)*64 + lane)*8 + j;
    ap[base]       = hi;
    ap[base + 512] = lo;
}

// ---------------- K3: padded group sums (reflect) ----------------
__global__ __launch_bounds__(256) void k_gsum(
    const float* __restrict__ x, float* __restrict__ ws)
{
    const int bid = blockIdx.x;            // bg*65 + pair
    const int pair = bid % 65;
    const int bg = bid / 65;               // b*16 + g
    const int t = threadIdx.x;
    const int half = t >> 7, tt = t & 127;
    const int yy = pair*2 + half;          // 0..129
    int sy = yy - 1; if (sy < 0) sy = -sy; if (sy > NH-1) sy = 2*(NH-1) - sy;
    const float* xbase = x + (size_t)bg * 16 * NPIX + (size_t)sy * NW;
    float* gp = ws + OFF_GP + ((size_t)bg * HP + yy) * HP;
    for (int xx = tt; xx < HP; xx += 128) {
        int sx = xx - 1; if (sx < 0) sx = -sx; if (sx > NW-1) sx = 2*(NW-1) - sx;
        float s = 0.f;
        #pragma unroll
        for (int k = 0; k < 16; k++) s += xbase[(size_t)k * NPIX + sx];
        gp[xx] = s;
    }
}

// ---------------- K4: instance-norm partial stats from Gp ----------------
__global__ __launch_bounds__(256) void k_stats(float* __restrict__ ws)
{
    const int g = blockIdx.x, b = blockIdx.y, chunk = blockIdx.z, t = threadIdx.x;
    __shared__ float kern_s[16*9];
    __shared__ float red[256*32];
    if (t < 144) kern_s[t] = ws[OFF_KERN + (b*NC + g*16)*9 + t];
    __syncthreads();

    float s[16], q[16];
    #pragma unroll
    for (int i = 0; i < 16; i++) { s[i] = 0.f; q[i] = 0.f; }

    const float* gp = ws + OFF_GP + (size_t)(b*16 + g) * HP * HP;
    const int p0b = chunk * 4096;
    for (int pi = 0; pi < 16; pi++) {
        const int p = p0b + pi*256 + t;
        const int y = p >> 7, xc = p & 127;
        const float* pa = gp + y*HP + xc;
        const float p0 = pa[0],    p1 = pa[1],      p2 = pa[2];
        const float p3 = pa[HP],   p4 = pa[HP+1],   p5 = pa[HP+2];
        const float p6 = pa[2*HP], p7 = pa[2*HP+1], p8 = pa[2*HP+2];
        #pragma unroll
        for (int ch = 0; ch < 16; ch++) {
            const float* k9 = kern_s + ch*9;
            float v = k9[0]*p0 + k9[1]*p1 + k9[2]*p2
                    + k9[3]*p3 + k9[4]*p4 + k9[5]*p5
                    + k9[6]*p6 + k9[7]*p7 + k9[8]*p8;
            s[ch] += v; q[ch] += v*v;
        }
    }
    #pragma unroll
    for (int ch = 0; ch < 16; ch++) { red[t*32 + ch] = s[ch]; red[t*32 + 16 + ch] = q[ch]; }
    for (int st = 128; st >= 1; st >>= 1) {
        __syncthreads();
        if (t < st) {
            #pragma unroll
            for (int v = 0; v < 32; v++) red[t*32 + v] += red[(t+st)*32 + v];
        }
    }
    __syncthreads();
    if (t < 32) {
        ws[OFF_PART + (size_t)((b*16 + g)*4 + chunk)*32 + t] = red[t];
    }
}

// ---------------- K5: finalize stats -> a, b2; compute att ----------------
__global__ __launch_bounds__(256) void k_fin(
    const float* __restrict__ w_ca2, float* __restrict__ ws)
{
    __shared__ float hm_s[128];
    const int b = blockIdx.x, c = threadIdx.x;
    if (c < 128) hm_s[c] = ws[OFF_HMID + b*128 + c];
    {
        const int g = c >> 4, ch = c & 15;
        const float* part = ws + OFF_PART + (size_t)(b*16 + g)*4*32;
        float S = 0.f, Q = 0.f;
        #pragma unroll
        for (int k = 0; k < 4; k++) { S += part[k*32 + ch]; Q += part[k*32 + 16 + ch]; }
        const float mean = S * (1.f/16384.f);
        const float var  = Q * (1.f/16384.f) - mean*mean;
        const float inv  = rsqrtf(var + 1e-5f);
        const float ga = ws[OFF_GAMMA + b*NC + c];
        const float be = ws[OFF_BETA  + b*NC + c];
        const float a  = ga * inv;
        ws[OFF_A  + b*NC + c] = a;
        ws[OFF_B2 + b*NC + c] = be - mean * a;
    }
    __syncthreads();
    {
        const float4* w4 = (const float4*)(w_ca2 + c*128);
        const float4* h4 = (const float4*)hm_s;
        float acc = 0.f;
        #pragma unroll
        for (int i = 0; i < 32; i++) {
            float4 a = h4[i], w = w4[i];
            acc += a.x*w.x + a.y*w.y + a.z*w.z + a.w*w.w;
        }
        ws[OFF_ATT + b*NC + c] = 1.f / (1.f + expf(-acc));
    }
}

// ---------------- K6: main fused kernel (phase B VALU + phase C MFMA) ----------------
// block: 256 threads = 4 waves; tile = (b, y, 64 px) x 256 out-channels
__global__ __launch_bounds__(256) void k_main(
    const float* __restrict__ x, const float* __restrict__ ws,
    const float* __restrict__ bias, float* __restrict__ out)
{
    // z_t: 64 px rows x 256 ch bf16, XOR-swizzled: byte = px*512 + (ch*2 ^ ((px&7)<<4))
    __shared__ unsigned short z_t[64*256];     // 32768 B
    __shared__ float bias_s[NC];               // 1024 B

    const int t = threadIdx.x;
    const int wave = t >> 6, lane = t & 63;
    const int x0 = blockIdx.x * 64, y = blockIdx.y, b = blockIdx.z;

    bias_s[t] = bias[t];

    char* zb = (char*)z_t;

    // ---- phase B: z = relu(a*conv + b2) + x*att, wave handles channels wave*64..+63 ----
    const float* kernG = ws + OFF_KERN + b*NC*9;
    const float* aG    = ws + OFF_A   + b*NC;
    const float* b2G   = ws + OFF_B2  + b*NC;
    const float* attG  = ws + OFF_ATT + b*NC;
    const float* gpB   = ws + OFF_GP + (size_t)b * 16 * HP * HP;
    const float* xB    = x + (size_t)b * NC * NPIX + (size_t)y * NW + x0 + lane;

    #pragma unroll
    for (int gi = 0; gi < 4; gi++) {
        const int g = wave*4 + gi;
        const float* gpr = gpB + ((size_t)g * HP + y) * HP + x0 + lane;
        const float p0 = gpr[0],    p1 = gpr[1],      p2 = gpr[2];
        const float p3 = gpr[HP],   p4 = gpr[HP+1],   p5 = gpr[HP+2];
        const float p6 = gpr[2*HP], p7 = gpr[2*HP+1], p8 = gpr[2*HP+2];
        #pragma unroll
        for (int ci = 0; ci < 16; ci++) {
            const int c = g*16 + ci;
            const float* k9 = kernG + c*9;   // wave-uniform -> s_load
            float conv = k9[0]*p0 + k9[1]*p1 + k9[2]*p2
                       + k9[3]*p3 + k9[4]*p4 + k9[5]*p5
                       + k9[6]*p6 + k9[7]*p7 + k9[8]*p8;
            const float xv = xB[(size_t)c * NPIX];
            float z = fmaxf(fmaf(aG[c], conv, b2G[c]), 0.f) + xv * attG[c];
            const int byte = lane*512 + ((c*2) ^ ((lane & 7) << 4));
            *(unsigned short*)(zb + byte) = f2bf(z);
        }
    }
    __syncthreads();

    // ---- phase C: out[o][px] = sum_c W[o][c] * z[c][px] via MFMA ----
    const unsigned short* ap = (const unsigned short*)(ws + OFF_APACK);
    f32x4 acc[4][4];
    #pragma unroll
    for (int mi = 0; mi < 4; mi++)
        #pragma unroll
        for (int ni = 0; ni < 4; ni++)
            acc[mi][ni] = (f32x4){0.f, 0.f, 0.f, 0.f};

    for (int ks = 0; ks < 8; ks++) {
        bf16x8 bfr[4];
        #pragma unroll
        for (int ni = 0; ni < 4; ni++) {
            const int px = ni*16 + (lane & 15);
            const int byte = px*512 + ((ks*64 + (lane >> 4)*16) ^ ((px & 7) << 4));
            bfr[ni] = *(const bf16x8*)(zb + byte);
        }
        #pragma unroll
        for (int mi = 0; mi < 4; mi++) {
            const int mt = wave*4 + mi;
            const bf16x8 ahi = *(const bf16x8*)(ap + ((size_t)((ks*16 + mt)*2    )*64 + lane)*8);
            const bf16x8 alo = *(const bf16x8*)(ap + ((size_t)((ks*16 + mt)*2 + 1)*64 + lane)*8);
            #pragma unroll
            for (int ni = 0; ni < 4; ni++) {
                acc[mi][ni] = __builtin_amdgcn_mfma_f32_16x16x32_bf16(ahi, bfr[ni], acc[mi][ni], 0, 0, 0);
                acc[mi][ni] = __builtin_amdgcn_mfma_f32_16x16x32_bf16(alo, bfr[ni], acc[mi][ni], 0, 0, 0);
            }
        }
    }

    // ---- epilogue: C layout col=lane&15 (px), row=(lane>>4)*4+reg (out) ----
    #pragma unroll
    for (int mi = 0; mi < 4; mi++) {
        const int o_base = wave*64 + mi*16 + (lane >> 4)*4;
        #pragma unroll
        for (int ni = 0; ni < 4; ni++) {
            const int px = x0 + ni*16 + (lane & 15);
            #pragma unroll
            for (int r = 0; r < 4; r++) {
                const int o = o_base + r;
                out[((size_t)(b*NC + o) * NH + y) * NW + px] = acc[mi][ni][r] + bias_s[o];
            }
        }
    }
}

extern "C" void kernel_launch(void* const* d_in, const int* in_sizes, int n_in,
                              void* d_out, int out_size, void* d_ws, size_t ws_size,
                              hipStream_t stream) {
    const float* x       = (const float*)d_in[0];
    const float* rep     = (const float*)d_in[1];
    const float* w_key   = (const float*)d_in[2];
    const float* w_gamma = (const float*)d_in[3];
    const float* w_beta  = (const float*)d_in[4];
    const float* w_ca1   = (const float*)d_in[5];
    const float* prelu_a = (const float*)d_in[6];
    const float* w_ca2   = (const float*)d_in[7];
    const float* w_conv2 = (const float*)d_in[8];
    const float* b_conv2 = (const float*)d_in[9];
    float* out = (float*)d_out;
    float* ws  = (float*)d_ws;

    k_params<<<dim3(46, NB), 256, 0, stream>>>(rep, w_key, w_gamma, w_beta, w_ca1, prelu_a, ws);
    k_pack<<<256, 256, 0, stream>>>(w_conv2, ws);
    k_gsum<<<NB*NGROUPS*65, 256, 0, stream>>>(x, ws);
    k_stats<<<dim3(NGROUPS, NB, 4), 256, 0, stream>>>(ws);
    k_fin<<<NB, 256, 0, stream>>>(w_ca2, ws);
    k_main<<<dim3(2, NH, NB), 256, 0, stream>>>(x, ws, b_conv2, out);
}